// Round 7
// baseline (99.681 us; speedup 1.0000x reference)
//
#include <hip/hip_runtime.h>
#include <math.h>

// B=256; bilinear upsample 64/32/16 -> 256x256 (align_corners=True), sum -> maps;
// 5x5 gaussian blur (sigma=4, reflect); per-sample max -> scores.
//
// v8: rolling y-state over LDS-materialized x-interp rows (fixes v7's LDS-pipe bound).
//   v7 counters: traffic ideal (3.8+65.6 MB) but 46 us at 1.5 TB/s -> LDS pipe bound
//   (16 ds_read_b32 + 4 b128 per sample ~141 cyc/wave-sample, ~26 us/CU).
//   Now: per block, x-interp ALL THREE scales' source rows into LDS xr0/xr1/xr2
//   (quad-vectorized: 3 scalar reads + 1 b128 write per 4 cols). Each wave then
//   rolls a y-state: per row 12 lerps in registers; source-row advance (prob
//   63/255, 31/255, 15/255 per scale) costs one aligned b128 -> amortized 0.43
//   b128/row (vs v7's 20 LDS ops/row). Rolling state = 24 floats + 20-float
//   window -> no spill (v3's spill came from per-thread x-params + raw lerps).
//   - QB=16 (16-row strips, 4 rows/wave); LDS 4768 floats = 19072 B -> 8 blocks/CU
//     = 32 waves/CU; grid 4096 = 16 work-blocks/CU
//   - 2 barriers total; control (y/rem) wave-uniform in SGPRs
//   - priming via 4 rolling steps (direct4-from-xr only for rw0==0 and tail rows)
//   - vertical 5-tap in registers; horizontal 5-tap via in-wave __shfl
//   - per-wave shuffle-reduce max -> part[bid*4+wv]
// Kernel 2: partials -> scores (deterministic).

static constexpr int W  = 256;
static constexpr int QB = 16;            // blocks per sample (16 rows each)

__device__ __forceinline__ int reflect256(int i) {
    if (i < 0) i = -i;
    if (i > 255) i = 510 - i;
    return i;
}

__global__ __launch_bounds__(256, 4) void fused_kernel(
    const float* __restrict__ in0,   // [B,64,64]
    const float* __restrict__ in1,   // [B,32,32]
    const float* __restrict__ in2,   // [B,16,16]
    float* __restrict__ part,        // [B*QB*4] per-wave partial maxes
    float* __restrict__ maps)        // [B,256,256]
{
    const int t   = threadIdx.x;
    const int q   = t & 63;                                      // lane = column quad
    const int wv  = __builtin_amdgcn_readfirstlane(t >> 6);      // wave id (SGPR)
    const int bid = blockIdx.x;
    const int b   = bid >> 4;
    const int r0  = (bid & 15) * 16;
    const int rw0 = r0 + wv * 4;                                 // wave's first output row
    const int c0  = q * 4;

    // ---- source-row slice bounds (block-uniform); output rows r0-2 .. r0+17 ----
    const int rlo = max(r0 - 2, 0);
    const int rhi = min(r0 + 17, 255);
    const int y0lo = (rlo * 63) / 255;
    const int y1lo = (rlo * 31) / 255;
    const int y2lo = (rlo * 15) / 255;
    const int y0hi = min((rhi * 63) / 255 + 1, 63);
    const int y1hi = min((rhi * 31) / 255 + 1, 31);
    const int y2hi = min((rhi * 15) / 255 + 1, 15);
    const int n0 = y0hi - y0lo + 1;      // <= 7
    const int n1 = y1hi - y1lo + 1;      // <= 5
    const int n2 = y2hi - y2lo + 1;      // <= 4

    // ---- LDS layout (floats), 4768 * 4 = 19072 B -> 8 blocks/CU (wave cap) ----
    // [0,448)      s0r raw 7x64
    // [448,608)    s1r raw 5x32
    // [608,672)    s2r raw 4x16
    // [672,2464)   xr0 7x256
    // [2464,3744)  xr1 5x256
    // [3744,4768)  xr2 4x256
    __shared__ float lds[4768];
    float* const s0r = lds;
    float* const s1r = lds + 448;
    float* const s2r = lds + 608;
    float* const xr0 = lds + 672;
    float* const xr1 = lds + 2464;
    float* const xr2 = lds + 3744;

    // ---- stage raw slices (float4, coalesced) ----
    {
        const float4* g0 = (const float4*)(in0 + (size_t)b * 4096 + y0lo * 64);
        const float4* g1 = (const float4*)(in1 + (size_t)b * 1024 + y1lo * 32);
        const float4* g2 = (const float4*)(in2 + (size_t)b * 256  + y2lo * 16);
        if (t < n0 * 16) ((float4*)s0r)[t] = g0[t];
        if (t < n1 * 8)  ((float4*)s1r)[t] = g1[t];
        if (t < n2 * 4)  ((float4*)s2r)[t] = g2[t];
    }
    __syncthreads();

    const float inv255 = 1.0f / 255.0f;

    // ---- x-interp phase (single, merged): quad-vectorized, 1 b128 write / 4 cols ----
    // For 4 consecutive out-cols the source span < 2, so reads {x0, x0+1, x0+2} suffice.
    {
        const int T0 = n0 * 64;              // scale0 tasks (row, quad)
        for (int task = t; task < T0; task += 256) {
            const int r = task >> 6, cq = (task & 63) * 4;
            const float* src = s0r + r * 64;
            const int x0 = (cq * 63) / 255;
            const float v0 = src[x0];
            const float v1 = src[min(x0 + 1, 63)];
            const float v2 = src[min(x0 + 2, 63)];
            float o[4];
#pragma unroll
            for (int k = 0; k < 4; ++k) {
                const int ix = (cq + k) * 63;
                const int xk = ix / 255;
                const float fx = (float)(ix - 255 * xk) * inv255;
                const float a  = (xk == x0) ? v0 : v1;
                const float bb = (xk == x0) ? v1 : v2;
                o[k] = a + fx * (bb - a);
            }
            *(float4*)(xr0 + r * 256 + cq) = make_float4(o[0], o[1], o[2], o[3]);
        }
        const int T1 = n1 * 64;              // scale1
        for (int task = t; task < T1; task += 256) {
            const int r = task >> 6, cq = (task & 63) * 4;
            const float* src = s1r + r * 32;
            const int x0 = (cq * 31) / 255;
            const float v0 = src[x0];
            const float v1 = src[min(x0 + 1, 31)];
            const float v2 = src[min(x0 + 2, 31)];
            float o[4];
#pragma unroll
            for (int k = 0; k < 4; ++k) {
                const int ix = (cq + k) * 31;
                const int xk = ix / 255;
                const float fx = (float)(ix - 255 * xk) * inv255;
                const float a  = (xk == x0) ? v0 : v1;
                const float bb = (xk == x0) ? v1 : v2;
                o[k] = a + fx * (bb - a);
            }
            *(float4*)(xr1 + r * 256 + cq) = make_float4(o[0], o[1], o[2], o[3]);
        }
        const int T2 = n2 * 64;              // scale2
        for (int task = t; task < T2; task += 256) {
            const int r = task >> 6, cq = (task & 63) * 4;
            const float* src = s2r + r * 16;
            const int x0 = (cq * 15) / 255;
            const float v0 = src[x0];
            const float v1 = src[min(x0 + 1, 15)];
            const float v2 = src[min(x0 + 2, 15)];
            float o[4];
#pragma unroll
            for (int k = 0; k < 4; ++k) {
                const int ix = (cq + k) * 15;
                const int xk = ix / 255;
                const float fx = (float)(ix - 255 * xk) * inv255;
                const float a  = (xk == x0) ? v0 : v1;
                const float bb = (xk == x0) ? v1 : v2;
                o[k] = a + fx * (bb - a);
            }
            *(float4*)(xr2 + r * 256 + cq) = make_float4(o[0], o[1], o[2], o[3]);
        }
    }
    __syncthreads();

    // ---- rolling bilinear state over xr rows (control wave-uniform -> SGPRs) ----
    auto ld0 = [&](int y, float* d) {
        const float4 v = *(const float4*)(xr0 + (y - y0lo) * 256 + c0);
        d[0] = v.x; d[1] = v.y; d[2] = v.z; d[3] = v.w;
    };
    auto ld1 = [&](int y, float* d) {
        const float4 v = *(const float4*)(xr1 + (y - y1lo) * 256 + c0);
        d[0] = v.x; d[1] = v.y; d[2] = v.z; d[3] = v.w;
    };
    auto ld2 = [&](int y, float* d) {
        const float4 v = *(const float4*)(xr2 + (y - y2lo) * 256 + c0);
        d[0] = v.x; d[1] = v.y; d[2] = v.z; d[3] = v.w;
    };

    int ya, yb, yc, rem0, rem1, rem2;
    float rl0[4], rh0[4], rl1[4], rh1[4], rl2[4], rh2[4];

    auto init_state = [&](int rn) {
        int iy;
        iy = rn * 63; ya = iy / 255; rem0 = iy - 255 * ya; ld0(ya, rl0); ld0(min(ya + 1, 63), rh0);
        iy = rn * 31; yb = iy / 255; rem1 = iy - 255 * yb; ld1(yb, rl1); ld1(min(yb + 1, 31), rh1);
        iy = rn * 15; yc = iy / 255; rem2 = iy - 255 * yc; ld2(yc, rl2); ld2(min(yc + 1, 15), rh2);
    };

    auto step = [&](float* o) {
        const float w0 = (float)rem0 * inv255;
        const float w1 = (float)rem1 * inv255;
        const float w2 = (float)rem2 * inv255;
#pragma unroll
        for (int k = 0; k < 4; ++k) {
            o[k] = (rl0[k] + w0 * (rh0[k] - rl0[k]))
                 + (rl1[k] + w1 * (rh1[k] - rl1[k]))
                 + (rl2[k] + w2 * (rh2[k] - rl2[k]));
        }
        // advance (wave-uniform; per-row increment < 1 -> at most one row each)
        rem0 += 63;
        if (rem0 >= 255) {
            rem0 -= 255; ++ya;
#pragma unroll
            for (int k = 0; k < 4; ++k) rl0[k] = rh0[k];
            ld0(min(ya + 1, 63), rh0);
        }
        rem1 += 31;
        if (rem1 >= 255) {
            rem1 -= 255; ++yb;
#pragma unroll
            for (int k = 0; k < 4; ++k) rl1[k] = rh1[k];
            ld1(min(yb + 1, 31), rh1);
        }
        rem2 += 15;
        if (rem2 >= 255) {
            rem2 -= 255; ++yc;
#pragma unroll
            for (int k = 0; k < 4; ++k) rl2[k] = rh2[k];
            ld2(min(yc + 1, 15), rh2);
        }
    };

    // full bilinear sample of map row rn (reflects internally), from xr rows
    auto direct4 = [&](int rn, float* o) {
        const int ry = reflect256(rn);
        int iy = ry * 63; int a0 = iy / 255; float w0 = (float)(iy - 255 * a0) * inv255; int a1 = min(a0 + 1, 63);
        int ib = ry * 31; int b0 = ib / 255; float w1 = (float)(ib - 255 * b0) * inv255; int b1 = min(b0 + 1, 31);
        int ic = ry * 15; int cc0 = ic / 255; float w2 = (float)(ic - 255 * cc0) * inv255; int cc1 = min(cc0 + 1, 15);
        float l0[4], h0[4], l1[4], h1[4], l2[4], h2[4];
        ld0(a0, l0); ld0(a1, h0);
        ld1(b0, l1); ld1(b1, h1);
        ld2(cc0, l2); ld2(cc1, h2);
#pragma unroll
        for (int k = 0; k < 4; ++k) {
            o[k] = (l0[k] + w0 * (h0[k] - l0[k]))
                 + (l1[k] + w1 * (h1[k] - l1[k]))
                 + (l2[k] + w2 * (h2[k] - l2[k]));
        }
    };

    // ---- gaussian weights (ksize=5, sigma=4) ----
    const float e1 = expf(-1.0f / 32.0f);
    const float e2 = expf(-4.0f / 32.0f);
    const float nrm = 1.0f + 2.0f * e1 + 2.0f * e2;
    const float gwc = 1.0f / nrm, gwa = e1 / nrm, gwb = e2 / nrm;

    // ---- prime 4-row blur window: map rows rw0-2 .. rw0+1 ----
    float m0[4], m1[4], m2[4], m3[4], mn[4];
    if (rw0 == 0) {                      // reflected top rows: -2 -> 2, -1 -> 1
        direct4(2, m0);
        direct4(1, m1);
        direct4(0, m2);
#pragma unroll
        for (int k = 0; k < 4; ++k) m3[k] = m1[k];
        init_state(2);                   // ready to produce rn = 2
    } else {
        init_state(rw0 - 2);
        step(m0); step(m1); step(m2); step(m3);   // state now at rn = rw0+2
    }

    float* __restrict__ mpr = maps + ((size_t)b * W + (size_t)rw0) * W + c0;
    *(float4*)(mpr)     = make_float4(m2[0], m2[1], m2[2], m2[3]);
    *(float4*)(mpr + W) = make_float4(m3[0], m3[1], m3[2], m3[3]);

    float gmax = -INFINITY;

#pragma unroll
    for (int i = 0; i < 4; ++i) {
        const int rn = rw0 + 2 + i;
        if (rn <= 255) step(mn);
        else           direct4(rn, mn);  // reflected rows 256/257 (last strip only)

        if (i < 2)                       // rows rw0+2, rw0+3 are ours
            *(float4*)(mpr + (size_t)(2 + i) * W) = make_float4(mn[0], mn[1], mn[2], mn[3]);

        // vertical 5-tap for blur row rw0+i (in registers)
        float vr0 = gwb * (m0[0] + mn[0]) + gwa * (m1[0] + m3[0]) + gwc * m2[0];
        float vr1 = gwb * (m0[1] + mn[1]) + gwa * (m1[1] + m3[1]) + gwc * m2[1];
        float vr2 = gwb * (m0[2] + mn[2]) + gwa * (m1[2] + m3[2]) + gwc * m2[2];
        float vr3 = gwb * (m0[3] + mn[3]) + gwa * (m1[3] + m3[3]) + gwc * m2[3];
#pragma unroll
        for (int k = 0; k < 4; ++k) { m0[k] = m1[k]; m1[k] = m2[k]; m2[k] = m3[k]; m3[k] = mn[k]; }

        // horizontal 5-tap: neighbor-quad edge columns via in-wave shuffles
        float az = __shfl_up(vr2, 1);        // col c0-2 from left lane
        float aw = __shfl_up(vr3, 1);        // col c0-1
        float cx = __shfl_down(vr0, 1);      // col c0+4 from right lane
        float cy = __shfl_down(vr1, 1);      // col c0+5
        float a2 = (q == 0)  ? vr2 : az;     // reflect at col 0
        float a3 = (q == 0)  ? vr1 : aw;
        float c4 = (q == 63) ? vr2 : cx;     // reflect at col 255
        float c5 = (q == 63) ? vr1 : cy;
        float o0 = gwc * vr0 + gwa * (a3 + vr1)  + gwb * (a2 + vr2);
        float o1 = gwc * vr1 + gwa * (vr0 + vr2) + gwb * (a3 + vr3);
        float o2 = gwc * vr2 + gwa * (vr1 + vr3) + gwb * (vr0 + c4);
        float o3 = gwc * vr3 + gwa * (vr2 + c4)  + gwb * (vr1 + c5);
        gmax = fmaxf(gmax, fmaxf(fmaxf(o0, o1), fmaxf(o2, o3)));
    }

    // ---- per-wave max -> partial (no extra barrier) ----
#pragma unroll
    for (int off = 32; off > 0; off >>= 1)
        gmax = fmaxf(gmax, __shfl_down(gmax, off));
    if (q == 0) part[bid * 4 + wv] = gmax;
}

__global__ void reduce_kernel(const float* __restrict__ part,
                              float* __restrict__ scores, int B) {
    int i = blockIdx.x * blockDim.x + threadIdx.x;
    if (i < B) {
        const float4* p = (const float4*)(part + 64 * i);   // QB*4 = 64 partials
        float m = -INFINITY;
#pragma unroll
        for (int k = 0; k < 16; ++k) {
            float4 v = p[k];
            m = fmaxf(m, fmaxf(fmaxf(v.x, v.y), fmaxf(v.z, v.w)));
        }
        scores[i] = m;
    }
}

extern "C" void kernel_launch(void* const* d_in, const int* in_sizes, int n_in,
                              void* d_out, int out_size, void* d_ws, size_t ws_size,
                              hipStream_t stream) {
    const float* in0 = (const float*)d_in[0];
    const float* in1 = (const float*)d_in[1];
    const float* in2 = (const float*)d_in[2];
    const int B = in_sizes[0] / (64 * 64);

    float* scores = (float*)d_out;
    float* maps   = (float*)d_out + B;
    float* part   = (float*)d_ws;          // B*QB*4 floats, fully rewritten each call

    hipLaunchKernelGGL(fused_kernel, dim3(B * QB), dim3(256), 0, stream,
                       in0, in1, in2, part, maps);
    hipLaunchKernelGGL(reduce_kernel, dim3((B + 255) / 256), dim3(256), 0, stream,
                       part, scores, B);
}